// Round 7
// baseline (3691.965 us; speedup 1.0000x reference)
//
#include <hip/hip_runtime.h>
#include <float.h>
#include <math.h>

// ---------------- problem constants ----------------
static constexpr int BATCH = 4;
static constexpr int NPT0  = 4096;   // N

// ---------------- workspace offsets (bytes) ----------------
static constexpr size_t OFF_F0T  = 0;         // [4][4096][8] f32
static constexpr size_t OFF_F1T  = 524288;    // [4][4096][32]
static constexpr size_t OFF_F2T  = 3670016;   // [4][2048][64]
static constexpr size_t OFF_F3T  = 5767168;   // [4][2048][64]
static constexpr size_t OFF_CQ1  = 8912896;   // [4][3][2048]
static constexpr size_t OFF_CQ2  = 9011200;   // [4][3][1024]
static constexpr size_t OFF_H    = 9060352;   // [4][Nq][16][Cout] 33.55MB -> ends 42614784
static constexpr size_t OFF_IDX1 = 42614784;  // [4][4096][16] i32
static constexpr size_t OFF_IDX2 = 43663360;  // [4][2048][16]
static constexpr size_t OFF_IDX3 = 44187648;  // [4][2048][16]
static constexpr size_t OFF_IDX4 = 44711936;  // [4][1024][16]
static constexpr size_t OFF_FPS1 = 44974080;  // [4][2048] i32
static constexpr size_t OFF_FPS2 = 45006848;  // [4][1024] i32
static constexpr size_t OFF_WD1  = 45023232;  // [32][8]
static constexpr size_t OFF_WD2  = 45024256;  // [64][32]
static constexpr size_t OFF_WD3  = 45032448;  // [64][64]
static constexpr size_t OFF_WD4  = 45048832;  // [128][64]
static constexpr size_t OFF_STAT = 45081600;  // 128 doubles
// part1 [4][4096][4][16]u64 = 8.39MB; parts 2/3/4 reuse its footprint after merge1.
static constexpr size_t OFF_PART  = 45099008;             // part1 ends 53487616
static constexpr size_t OFF_PART2 = OFF_PART;             // 4.19MB
static constexpr size_t OFF_PART3 = OFF_PART + 4194304;   // 2.10MB
static constexpr size_t OFF_PART4 = OFF_PART + 6291456;   // 2.10MB
static constexpr size_t OFF_CAND0 = 53487616;             // [4][4096] float4 = 256KB
static constexpr size_t OFF_CAND1 = 53749760;             // [4][2048] float4 = 128KB -> ends 53880832

// d_out offsets (floats): coor | f | xyz1 | point1 | inpc_f
static constexpr size_t OUT_COOR = 0;        // [4][3][1024]
static constexpr size_t OUT_F    = 12288;    // [4][128][1024]
static constexpr size_t OUT_XYZ1 = 536576;   // [4][3][2048]
static constexpr size_t OUT_PT1  = 561152;   // [4][64][2048]
static constexpr size_t OUT_INPC = 1085440;  // [4][8][4096]

// ---------------- DPP wave-max on u64 keys ----------------
template<int CTRL>
__device__ __forceinline__ unsigned long long dpp_max64(unsigned long long k) {
  unsigned lo = (unsigned)k, hi = (unsigned)(k >> 32);
  unsigned olo = (unsigned)__builtin_amdgcn_update_dpp((int)lo, (int)lo, CTRL, 0xF, 0xF, false);
  unsigned ohi = (unsigned)__builtin_amdgcn_update_dpp((int)hi, (int)hi, CTRL, 0xF, 0xF, false);
  unsigned long long o = ((unsigned long long)ohi << 32) | olo;
  return o > k ? o : k;
}

// ---------------- prep: zero stats + weight deltas ----------------
__device__ __forceinline__ void prep_dev(
    int vb, const float* __restrict__ w1, const float* __restrict__ w2,
    const float* __restrict__ w3, const float* __restrict__ w4,
    float* __restrict__ wd1, float* __restrict__ wd2,
    float* __restrict__ wd3, float* __restrict__ wd4,
    double* __restrict__ stats)
{
  int t = vb * 256 + threadIdx.x;
  if (t < 128) stats[t] = 0.0;
  if (t < 32 * 8)   { int o = t / 8,  c = t % 8;  wd1[t] = w1[o*16  + 8   + c] - w1[o*16  + c]; }
  if (t < 64 * 32)  { int o = t / 32, c = t % 32; wd2[t] = w2[o*64  + 32  + c] - w2[o*64  + c]; }
  if (t < 64 * 64)  { int o = t / 64, c = t % 64; wd3[t] = w3[o*128 + 64  + c] - w3[o*128 + c]; }
  if (t < 128 * 64) { int o = t / 64, c = t % 64; wd4[t] = w4[o*128 + 64  + c] - w4[o*128 + c]; }
}

// ---------------- input linear ----------------
__device__ __forceinline__ void linear_dev(
    int vb, const float* __restrict__ x, const float* __restrict__ w_in,
    const float* __restrict__ b_in, float* __restrict__ f0t,
    float* __restrict__ out_inpc)
{
  int t = vb * 256 + threadIdx.x;
  int n = t & (NPT0 - 1);
  int b = t >> 12;
  float x0 = x[(size_t)b*3*NPT0 + n];
  float x1 = x[(size_t)b*3*NPT0 + NPT0 + n];
  float x2 = x[(size_t)b*3*NPT0 + 2*NPT0 + n];
#pragma unroll
  for (int o = 0; o < 8; ++o) {
    float v = __fmul_rn(w_in[o*3], x0);
    v = fmaf(w_in[o*3+1], x1, v);
    v = fmaf(w_in[o*3+2], x2, v);
    v = __fadd_rn(v, b_in[o]);
    f0t[(size_t)t * 8 + o] = v;
    out_inpc[((size_t)b*8 + o)*NPT0 + n] = v;
  }
}

// ---- kNN partial (packed candidates, 512 threads): top-16 per (q, CS slice) --
// key = (flipbits(d) << 32) | j : ascending == (d asc, idx asc) == lax.top_k ties.
template<int CS>
__device__ __forceinline__ void knnp_pack_dev512(
    int vb, const float* __restrict__ cq, const float4* __restrict__ candPack,
    unsigned long long* __restrict__ part, int Nq, int Nk)
{
  const int slices = Nk / CS;
  int s  = vb % slices;
  int r  = vb / slices;
  int qb = r % (Nq >> 9);
  int b  = r / (Nq >> 9);
  int t  = threadIdx.x;
  int q  = qb*512 + t;
  const float* cqb = cq + (size_t)b*3*Nq;
  float qx = cqb[q], qy = cqb[Nq + q], qz = cqb[2*Nq + q];
  float sqq = __fadd_rn(__fadd_rn(__fmul_rn(qx,qx), __fmul_rn(qy,qy)), __fmul_rn(qz,qz));

  const float4* cp = candPack + (size_t)b*Nk + s*CS;
  int jbase = s*CS;

  unsigned long long bd[16];
#pragma unroll
  for (int sl = 0; sl < 16; ++sl) bd[sl] = ~0ull;
  unsigned long long wk = ~0ull; int ws = 0;

#pragma unroll 4
  for (int jj = 0; jj < CS; ++jj) {
    float4 c = cp[jj];                       // wave-uniform -> scalar load
    float dot = __fmul_rn(c.x, qx);
    dot = fmaf(c.y, qy, dot);
    dot = fmaf(c.z, qz, dot);
    float d = __fsub_rn(__fadd_rn(sqq, c.w), __fmul_rn(2.0f, dot));
    unsigned u = __float_as_uint(d);
    u ^= (0x80000000u | (unsigned)((int)u >> 31));
    unsigned long long key = ((unsigned long long)u << 32) | (unsigned)(jbase + jj);
    if (key < wk) {
      unsigned long long nw = 0; int nws = 0;
#pragma unroll
      for (int sl = 0; sl < 16; ++sl) {
        bool rep = (sl == ws);
        unsigned long long v = rep ? key : bd[sl];
        bd[sl] = v;
        bool g = v > nw;
        nw = g ? v : nw; nws = g ? sl : nws;
      }
      wk = nw; ws = nws;
    }
  }
  unsigned long long* op = part + (((size_t)b*Nq + q)*(size_t)slices + s)*16;
#pragma unroll
  for (int sl = 0; sl < 16; ++sl) op[sl] = bd[sl];
}

// ---- kNN partial (LDS-staged, 256 thr) — only where no FPS co-runs (knn4) --
__device__ __forceinline__ void knnp_lds_dev(
    int vb, const float* __restrict__ cq, const float* __restrict__ ck,
    unsigned long long* __restrict__ part, int Nq, int Nk, int slices, void* smem)
{
  const int CS = 512;
  int s  = vb % slices;
  int r  = vb / slices;
  int qb = r % (Nq >> 8);
  int b  = r / (Nq >> 8);
  float4* cand = (float4*)smem;
  int t = threadIdx.x;
  const float* ckb = ck + (size_t)b*3*Nk;
  for (int jj = t; jj < CS; jj += 256) {
    int j = s*CS + jj;
    float xx = ckb[j], yy = ckb[Nk + j], zz = ckb[2*Nk + j];
    float sq = __fadd_rn(__fadd_rn(__fmul_rn(xx,xx), __fmul_rn(yy,yy)), __fmul_rn(zz,zz));
    cand[jj] = make_float4(xx, yy, zz, sq);
  }
  __syncthreads();
  int q = qb*256 + t;
  const float* cqb = cq + (size_t)b*3*Nq;
  float qx = cqb[q], qy = cqb[Nq + q], qz = cqb[2*Nq + q];
  float sqq = __fadd_rn(__fadd_rn(__fmul_rn(qx,qx), __fmul_rn(qy,qy)), __fmul_rn(qz,qz));

  unsigned long long bd[16];
#pragma unroll
  for (int sl = 0; sl < 16; ++sl) bd[sl] = ~0ull;
  unsigned long long wk = ~0ull; int ws = 0;

  for (int jj = 0; jj < CS; ++jj) {
    float4 c = cand[jj];
    float dot = __fmul_rn(c.x, qx);
    dot = fmaf(c.y, qy, dot);
    dot = fmaf(c.z, qz, dot);
    float d = __fsub_rn(__fadd_rn(sqq, c.w), __fmul_rn(2.0f, dot));
    unsigned u = __float_as_uint(d);
    u ^= (0x80000000u | (unsigned)((int)u >> 31));
    unsigned long long key = ((unsigned long long)u << 32) | (unsigned)(s*CS + jj);
    if (key < wk) {
      unsigned long long nw = 0; int nws = 0;
#pragma unroll
      for (int sl = 0; sl < 16; ++sl) {
        bool rep = (sl == ws);
        unsigned long long v = rep ? key : bd[sl];
        bd[sl] = v;
        bool g = v > nw;
        nw = g ? v : nw; nws = g ? sl : nws;
      }
      wk = nw; ws = nws;
    }
  }
  unsigned long long* op = part + (((size_t)b*Nq + q)*(size_t)slices + s)*16;
#pragma unroll
  for (int sl = 0; sl < 16; ++sl) op[sl] = bd[sl];
}

// ---------------- kNN merge: 16 smallest of slices*16 ----------
__device__ __forceinline__ void merge_dev(
    int vb, const unsigned long long* __restrict__ part, int* __restrict__ idx,
    int slices)
{
  int t = vb * 256 + threadIdx.x;
  const unsigned long long* ip = part + (size_t)t * slices * 16;
  unsigned long long bd[16];
#pragma unroll
  for (int sl = 0; sl < 16; ++sl) bd[sl] = ~0ull;
  unsigned long long wk = ~0ull; int ws = 0;
  int n = slices * 16;
  for (int i = 0; i < n; ++i) {
    unsigned long long key = ip[i];
    if (key < wk) {
      unsigned long long nw = 0; int nws = 0;
#pragma unroll
      for (int sl = 0; sl < 16; ++sl) {
        bool rep = (sl == ws);
        unsigned long long v = rep ? key : bd[sl];
        bd[sl] = v;
        bool g = v > nw;
        nw = g ? v : nw; nws = g ? sl : nws;
      }
      wk = nw; ws = nws;
    }
  }
  int* op = idx + (size_t)t * 16;
#pragma unroll
  for (int sl = 0; sl < 16; ++sl) op[sl] = (int)(bd[sl] & 0xFFFFFFFFull);
}

// ------- FPS: NTHR threads (low per-thread state), DPP wave reduce ----------
// key = (bits(nd) << 32) | ~j ; max key == max nd, ties -> lowest j (argmax).
template<int NN, int PPT, int NTHR>
__device__ __forceinline__ void fps_dev(
    int b, const float* __restrict__ coor, int m, int* __restrict__ fidx_all,
    float* __restrict__ ca_all, float* __restrict__ co_all, void* smem)
{
  constexpr int WAVES = NTHR / 64;
  float* sx = (float*)smem;
  float* sy = sx + NN;
  float* sz = sy + NN;
  unsigned long long* part = (unsigned long long*)(sz + NN);  // [2][WAVES]
  int t = threadIdx.x, lane = t & 63, wv = t >> 6;
  const float* cb = coor + (size_t)b*3*NN;
  float px[PPT], py[PPT], pz[PPT], pd[PPT];
#pragma unroll
  for (int i = 0; i < PPT; ++i) {
    int j = i*NTHR + t;
    px[i] = cb[j]; py[i] = cb[NN + j]; pz[i] = cb[2*NN + j];
    pd[i] = 1e10f;
    sx[j] = px[i]; sy[j] = py[i]; sz[j] = pz[i];
  }
  __syncthreads();
  float cx = sx[0], cy = sy[0], cz = sz[0];
  int* fidx = fidx_all + b*m;
  float* ca = ca_all + (size_t)b*3*m;
  float* co = co_all + (size_t)b*3*m;
  int cur = 0, par = 0;
  for (int it = 0; it < m; ++it) {
    if (t == 0) {
      fidx[it] = cur;
      ca[it] = cx; ca[m + it] = cy; ca[2*m + it] = cz;
      co[it] = cx; co[m + it] = cy; co[2*m + it] = cz;
    }
    float bv = -1.0f; int bslot = 0;
#pragma unroll
    for (int i = 0; i < PPT; ++i) {
      float dx = __fsub_rn(px[i], cx);
      float dy = __fsub_rn(py[i], cy);
      float dz = __fsub_rn(pz[i], cz);
      float d = __fadd_rn(__fadd_rn(__fmul_rn(dx,dx), __fmul_rn(dy,dy)), __fmul_rn(dz,dz));
      float nd = fminf(pd[i], d);
      pd[i] = nd;
      bool g = nd > bv;
      bv = g ? nd : bv;
      bslot = g ? i : bslot;
    }
    unsigned bij = ~(unsigned)(bslot * NTHR + t);
    unsigned long long k = ((unsigned long long)__float_as_uint(bv) << 32) | bij;
    k = dpp_max64<0x111>(k);   // row_shr:1
    k = dpp_max64<0x112>(k);   // row_shr:2
    k = dpp_max64<0x114>(k);   // row_shr:4
    k = dpp_max64<0x118>(k);   // row_shr:8
    k = dpp_max64<0x142>(k);   // row_bcast:15
    k = dpp_max64<0x143>(k);   // row_bcast:31  -> lane 63 has wave max
    unsigned wlo = (unsigned)__builtin_amdgcn_readlane((int)(unsigned)k, 63);
    unsigned whi = (unsigned)__builtin_amdgcn_readlane((int)(unsigned)(k >> 32), 63);
    if (lane == 0) part[par*WAVES + wv] = ((unsigned long long)whi << 32) | wlo;
    __syncthreads();
    unsigned long long k0 = part[par*WAVES + 0];
#pragma unroll
    for (int w = 1; w < WAVES; ++w) {
      unsigned long long kw = part[par*WAVES + w];
      k0 = kw > k0 ? kw : k0;
    }
    cur = (int)(~(unsigned)(k0 & 0xFFFFFFFFull));
    cx = sx[cur]; cy = sy[cur]; cz = sz[cur];
    par ^= 1;   // double-buffered partials -> single barrier per step
  }
}

// ------- fused (optional FPS-gather) + graph-conv + fp64 GN stats ----------
// tid: 256-wide sub-block thread id (aligned to 4 waves); smem: per-sub-block.
template<int C, int COUT, int OC>
__device__ __forceinline__ void passA_dev(
    int vb, int tid, const float* __restrict__ xq, const float* __restrict__ xk,
    const int* __restrict__ idx, const float* __restrict__ w,
    const float* __restrict__ wdl, float* __restrict__ h,
    double* __restrict__ stats, int Nq, int Nk,
    const int* __restrict__ qmap, int NqSrc, void* smem)
{
  constexpr int NCH = COUT / OC;
  constexpr int GS  = COUT / 4;
  float* sxq   = (float*)smem;          // [16][C]
  float* sbase = sxq + 16*C;            // [16][COUT+1]
  int qb = Nq >> 4;
  int b = vb / qb, nb = vb % qb;
  int n0 = nb << 4;
  int t = tid;
  for (int i = t; i < 16*C; i += 256) {
    int nn = i / C, cc = i % C;
    int qrow = qmap ? qmap[b*Nq + n0 + nn] : (n0 + nn);
    sxq[nn*C + cc] = xq[((size_t)b*NqSrc + qrow)*C + cc];
  }
  __syncthreads();
  for (int i = t; i < 16*COUT; i += 256) {
    int nn = i / COUT, o = i % COUT;
    float acc = 0.f;
#pragma unroll 4
    for (int c = 0; c < C; ++c) acc = fmaf(wdl[o*C + c], sxq[nn*C + c], acc);
    sbase[nn*(COUT+1) + o] = acc;
  }
  __syncthreads();
  int lane = t & 63;
  int n_loc = t >> 4, kk = t & 15;
  int kidx = idx[((size_t)b*Nq + n0 + n_loc)*16 + kk];
  const float* xr = xk + ((size_t)b*Nk + kidx)*C;
  float* hrow = h + (((size_t)b*Nq + n0 + n_loc)*16 + kk)*(size_t)COUT;
#pragma unroll 1
  for (int oc = 0; oc < NCH; ++oc) {
    int o0 = oc * OC;
    float acc[OC];
#pragma unroll
    for (int oi = 0; oi < OC; ++oi) acc[oi] = sbase[n_loc*(COUT+1) + o0 + oi];
#pragma unroll 1
    for (int c4 = 0; c4 < C/4; ++c4) {
      float4 v = *(const float4*)(xr + c4*4);
#pragma unroll
      for (int oi = 0; oi < OC; ++oi) {
        const float* wr = w + (size_t)(o0 + oi)*(2*C) + c4*4;  // wave-uniform
        acc[oi] = fmaf(wr[0], v.x, acc[oi]);
        acc[oi] = fmaf(wr[1], v.y, acc[oi]);
        acc[oi] = fmaf(wr[2], v.z, acc[oi]);
        acc[oi] = fmaf(wr[3], v.w, acc[oi]);
      }
    }
#pragma unroll
    for (int oi = 0; oi < OC; ++oi) hrow[o0 + oi] = acc[oi];
    double s = 0.0, s2 = 0.0;
#pragma unroll
    for (int oi = 0; oi < OC; ++oi) { double dv = (double)acc[oi]; s += dv; s2 += dv*dv; }
#pragma unroll
    for (int mm = 1; mm < 64; mm <<= 1) {
      s  += __shfl_xor(s,  mm, 64);
      s2 += __shfl_xor(s2, mm, 64);
    }
    if (lane == 0) {
      int g = o0 / GS;
      atomicAdd(&stats[((size_t)b*4 + g)*2],     s);
      atomicAdd(&stats[((size_t)b*4 + g)*2 + 1], s2);
    }
  }
}

template<int C, int COUT, int OC>
__global__ __launch_bounds__(256) void k_passA(
    const float* __restrict__ xq, const float* __restrict__ xk,
    const int* __restrict__ idx, const float* __restrict__ w,
    const float* __restrict__ wdl, float* __restrict__ h,
    double* __restrict__ stats, int Nq, int Nk,
    const int* __restrict__ qmap, int NqSrc)
{
  extern __shared__ char smem[];
  passA_dev<C,COUT,OC>(blockIdx.x, threadIdx.x, xq, xk, idx, w, wdl, h, stats,
                       Nq, Nk, qmap, NqSrc, smem);
}

// -------- pass B with inline GN finalize: normalize + leaky + max over k ----
__device__ __forceinline__ void passB_dev(
    int vb, const float* __restrict__ h, const double* __restrict__ stats,
    const float* __restrict__ gw, const float* __restrict__ gb,
    float* __restrict__ ft, float* __restrict__ ocn, int Nq, int COUT)
{
  int t = vb * 256 + threadIdx.x;
  int o = t % COUT;
  int r = t / COUT;
  int n = r % Nq;
  int b = r / Nq;
  int GS = COUT / 4, g = o / GS;
  double cnt = (double)GS * (double)Nq * 16.0;
  double su = stats[((size_t)b*4 + g)*2];
  double s2 = stats[((size_t)b*4 + g)*2 + 1];
  double mean = su / cnt;
  double var = s2 / cnt - mean * mean;
  float vf = (float)var; if (vf < 0.f) vf = 0.f;
  float inv = 1.0f / sqrtf(vf + 1e-5f);
  float A = gw[o] * inv;
  float Bb = gb[o] - (float)mean * A;
  const float* hp = h + (((size_t)b*Nq + n)*16)*(size_t)COUT + o;
  float m = -FLT_MAX;
#pragma unroll
  for (int k = 0; k < 16; ++k) {
    float v = hp[(size_t)k*COUT];
    float y = fmaf(v, A, Bb);
    y = (y >= 0.f) ? y : 0.2f*y;
    m = fmaxf(m, y);
  }
  if (ft)  ft[((size_t)b*Nq + n)*COUT + o] = m;
  if (ocn) ocn[((size_t)b*COUT + o)*Nq + n] = m;
}

__global__ __launch_bounds__(256) void k_passB(
    const float* __restrict__ h, const double* __restrict__ stats,
    const float* __restrict__ gw, const float* __restrict__ gb,
    float* __restrict__ ft, float* __restrict__ ocn, int Nq, int COUT)
{
  passB_dev(blockIdx.x, h, stats, gw, gb, ft, ocn, Nq, COUT);
}

// ---- PRE: pack0(x) || prep || linear_in ------------------------------------
__global__ __launch_bounds__(256) void k_pre(
    const float* __restrict__ x, const float* __restrict__ w_in,
    const float* __restrict__ b_in, float* __restrict__ f0t,
    float* __restrict__ outInpc,
    const float* __restrict__ w1, const float* __restrict__ w2,
    const float* __restrict__ w3, const float* __restrict__ w4,
    float* __restrict__ wd1, float* __restrict__ wd2,
    float* __restrict__ wd3, float* __restrict__ wd4,
    double* __restrict__ stats, float4* __restrict__ cand0)
{
  int vb = blockIdx.x;
  if (vb < 64) {
    int g = vb*256 + threadIdx.x;       // [0,16384)
    int b = g >> 12, n = g & 4095;
    const float* xb = x + (size_t)b*3*4096;
    float xx = xb[n], yy = xb[4096 + n], zz = xb[2*4096 + n];
    float sq = __fadd_rn(__fadd_rn(__fmul_rn(xx,xx), __fmul_rn(yy,yy)), __fmul_rn(zz,zz));
    cand0[g] = make_float4(xx, yy, zz, sq);
  }
  else if (vb < 96) prep_dev(vb - 64, w1, w2, w3, w4, wd1, wd2, wd3, wd4, stats);
  else              linear_dev(vb - 96, x, w_in, b_in, f0t, outInpc);
}

// ---- MEGA A (512 thr): FPS1 || knn1 partials (packed) ----------------------
__global__ __launch_bounds__(512) void k_megaA(
    const float* __restrict__ x, int* __restrict__ fps1,
    float* __restrict__ cq1, float* __restrict__ outXyz1,
    const float4* __restrict__ cand0, unsigned long long* __restrict__ part1)
{
  extern __shared__ char smem[];
  int vb = blockIdx.x;
  if (vb < 4) fps_dev<4096,8,512>(vb, x, 2048, fps1, cq1, outXyz1, smem);
  else        knnp_pack_dev512<1024>(vb - 4, x, cand0, part1, 4096, 4096);
}

// ---- MERGE-P: merge1 || pack1(cq1) -----------------------------------------
__global__ __launch_bounds__(256) void k_mergeP(
    const unsigned long long* __restrict__ part1, int* __restrict__ idx1,
    const float* __restrict__ cq1, float4* __restrict__ cand1)
{
  int vb = blockIdx.x;
  if (vb < 64) merge_dev(vb, part1, idx1, 4);
  else {
    int g = (vb - 64)*256 + threadIdx.x;   // [0,8192)
    int b = g >> 11, n = g & 2047;
    const float* cb = cq1 + (size_t)b*3*2048;
    float xx = cb[n], yy = cb[2048 + n], zz = cb[2*2048 + n];
    float sq = __fadd_rn(__fadd_rn(__fmul_rn(xx,xx), __fmul_rn(yy,yy)), __fmul_rn(zz,zz));
    cand1[g] = make_float4(xx, yy, zz, sq);
  }
}

// ---- MEGA B (512 thr): FPS2 || knn2p || knn3p || passA1 (2 sub-blocks) -----
__global__ __launch_bounds__(512) void k_megaB(
    const float* __restrict__ cq1, const float4* __restrict__ cand0,
    const float4* __restrict__ cand1,
    int* __restrict__ fps2, float* __restrict__ cq2, float* __restrict__ outCoor,
    unsigned long long* __restrict__ part2, unsigned long long* __restrict__ part3,
    const float* __restrict__ f0t, const int* __restrict__ idx1,
    const float* __restrict__ w1, const float* __restrict__ wd1,
    float* __restrict__ h, double* __restrict__ st1)
{
  extern __shared__ char smem[];
  int vb = blockIdx.x;
  if      (vb < 4)         fps_dev<2048,4,512>(vb, cq1, 1024, fps2, cq2, outCoor, smem);
  else if (vb < 4 + 64)    knnp_pack_dev512<1024>(vb - 4,  cq1, cand0, part2, 2048, 4096);
  else if (vb < 4 + 64+32) knnp_pack_dev512<1024>(vb - 68, cq1, cand1, part3, 2048, 2048);
  else {
    // two aligned 256-thread sub-blocks; identical uniform control flow ->
    // the __syncthreads inside passA_dev stay barrier-count aligned.
    int sub = threadIdx.x >> 8;
    int tid = threadIdx.x & 255;
    int vpa = (vb - 100)*2 + sub;        // [0,1024)
    passA_dev<8,32,8>(vpa, tid, f0t, f0t, idx1, w1, wd1,
                      h, st1, 4096, 4096, nullptr, 4096, smem + sub*2624);
  }
}

// ---- MEGA C: knn4p (LDS) || merge2 || merge3 || passB1 ---------------------
__global__ __launch_bounds__(256) void k_megaC(
    const float* __restrict__ cq2, const float* __restrict__ cq1,
    unsigned long long* __restrict__ part4,
    const unsigned long long* __restrict__ part2, int* __restrict__ idx2,
    const unsigned long long* __restrict__ part3, int* __restrict__ idx3,
    const float* __restrict__ h, const double* __restrict__ st1,
    const float* __restrict__ g1w, const float* __restrict__ g1b,
    float* __restrict__ f1t)
{
  extern __shared__ char smem[];
  int vb = blockIdx.x;
  if      (vb < 64)  knnp_lds_dev(vb, cq2, cq1, part4, 1024, 2048, 4, smem);
  else if (vb < 96)  merge_dev(vb - 64, part2, idx2, 4);
  else if (vb < 128) merge_dev(vb - 96, part3, idx3, 2);
  else               passB_dev(vb - 128, h, st1, g1w, g1b, f1t, nullptr, 4096, 32);
}

// ---- MEGA D: merge4 || passA2 (FPS1-gathered xq) ---------------------------
__global__ __launch_bounds__(256) void k_megaD(
    const unsigned long long* __restrict__ part4, int* __restrict__ idx4,
    const float* __restrict__ f1t, const int* __restrict__ idx2,
    const float* __restrict__ w2, const float* __restrict__ wd2,
    float* __restrict__ h, double* __restrict__ st2,
    const int* __restrict__ fps1)
{
  extern __shared__ char smem[];
  int vb = blockIdx.x;
  if (vb < 16) merge_dev(vb, part4, idx4, 4);
  else         passA_dev<32,64,16>(vb - 16, threadIdx.x, f1t, f1t, idx2, w2, wd2,
                                   h, st2, 2048, 4096, fps1, 4096, smem);
}

// ---------------- launch ----------------
extern "C" void kernel_launch(void* const* d_in, const int* in_sizes, int n_in,
                              void* d_out, int out_size, void* d_ws, size_t ws_size,
                              hipStream_t stream)
{
  (void)in_sizes; (void)n_in; (void)out_size; (void)ws_size;
  const float* x    = (const float*)d_in[0];
  const float* w_in = (const float*)d_in[1];
  const float* b_in = (const float*)d_in[2];
  const float* w1   = (const float*)d_in[3];
  const float* g1w  = (const float*)d_in[4];
  const float* g1b  = (const float*)d_in[5];
  const float* w2   = (const float*)d_in[6];
  const float* g2w  = (const float*)d_in[7];
  const float* g2b  = (const float*)d_in[8];
  const float* w3   = (const float*)d_in[9];
  const float* g3w  = (const float*)d_in[10];
  const float* g3b  = (const float*)d_in[11];
  const float* w4   = (const float*)d_in[12];
  const float* g4w  = (const float*)d_in[13];
  const float* g4b  = (const float*)d_in[14];
  float* out = (float*)d_out;
  char*  wsb = (char*)d_ws;

  float* f0t  = (float*)(wsb + OFF_F0T);
  float* f1t  = (float*)(wsb + OFF_F1T);
  float* f2t  = (float*)(wsb + OFF_F2T);
  float* f3t  = (float*)(wsb + OFF_F3T);
  float* cq1  = (float*)(wsb + OFF_CQ1);
  float* cq2  = (float*)(wsb + OFF_CQ2);
  float* h    = (float*)(wsb + OFF_H);
  int*   idx1 = (int*)(wsb + OFF_IDX1);
  int*   idx2 = (int*)(wsb + OFF_IDX2);
  int*   idx3 = (int*)(wsb + OFF_IDX3);
  int*   idx4 = (int*)(wsb + OFF_IDX4);
  int*   fps1 = (int*)(wsb + OFF_FPS1);
  int*   fps2 = (int*)(wsb + OFF_FPS2);
  float* wd1  = (float*)(wsb + OFF_WD1);
  float* wd2  = (float*)(wsb + OFF_WD2);
  float* wd3  = (float*)(wsb + OFF_WD3);
  float* wd4  = (float*)(wsb + OFF_WD4);
  double* statAll = (double*)(wsb + OFF_STAT);
  double* st1 = statAll, *st2 = statAll + 32, *st3 = statAll + 64, *st4 = statAll + 96;
  unsigned long long* part1 = (unsigned long long*)(wsb + OFF_PART);
  unsigned long long* part2 = (unsigned long long*)(wsb + OFF_PART2);
  unsigned long long* part3 = (unsigned long long*)(wsb + OFF_PART3);
  unsigned long long* part4 = (unsigned long long*)(wsb + OFF_PART4);
  float4* cand0 = (float4*)(wsb + OFF_CAND0);
  float4* cand1 = (float4*)(wsb + OFF_CAND1);

  float* outCoor = out + OUT_COOR;
  float* outF    = out + OUT_F;
  float* outXyz1 = out + OUT_XYZ1;
  float* outPt1  = out + OUT_PT1;
  float* outInpc = out + OUT_INPC;

  // PRE: pack0 || prep || linear_in
  k_pre<<<160, 256, 0, stream>>>(x, w_in, b_in, f0t, outInpc,
      w1, w2, w3, w4, wd1, wd2, wd3, wd4, statAll, cand0);

  // A: FPS1 (512thr, PPT=8) || knn1p (128 x 512thr)
  k_megaA<<<132, 512, 49280, stream>>>(x, fps1, cq1, outXyz1, cand0, part1);

  // merge1 || pack1
  k_mergeP<<<96, 256, 0, stream>>>(part1, idx1, cq1, cand1);

  // B: FPS2 (512thr, PPT=4) || knn2p || knn3p || passA1 (2x256 sub-blocks)
  k_megaB<<<612, 512, 24704, stream>>>(
      cq1, cand0, cand1, fps2, cq2, outCoor, part2, part3, f0t, idx1, w1, wd1, h, st1);

  // C: knn4p || merge2 || merge3 || passB1
  k_megaC<<<2176, 256, 8192, stream>>>(
      cq2, cq1, part4, part2, idx2, part3, idx3, h, st1, g1w, g1b, f1t);

  // D: merge4 || passA2
  k_megaD<<<528, 256, 6208, stream>>>(part4, idx4, f1t, idx2, w2, wd2, h, st2, fps1);

  // stage 2/3/4 tail
  k_passB<<<2048, 256, 0, stream>>>(h, st2, g2w, g2b, f2t, outPt1, 2048, 64);
  k_passA<64,64,16><<<512, 256, 8256, stream>>>(f2t, f2t, idx3, w3, wd3, h, st3,
                                                2048, 2048, nullptr, 2048);
  k_passB<<<2048, 256, 0, stream>>>(h, st3, g3w, g3b, f3t, nullptr, 2048, 64);
  k_passA<64,128,16><<<256, 256, 12352, stream>>>(f3t, f3t, idx4, w4, wd4, h, st4,
                                                  1024, 2048, fps2, 2048);
  k_passB<<<2048, 256, 0, stream>>>(h, st4, g4w, g4b, nullptr, outF, 1024, 128);
}

// Round 8
// 3030.751 us; speedup vs baseline: 1.2182x; 1.2182x over previous
//
#include <hip/hip_runtime.h>
#include <float.h>
#include <math.h>

// ---------------- problem constants ----------------
static constexpr int BATCH = 4;
static constexpr int NPT0  = 4096;   // N

// ---------------- workspace offsets (bytes) ----------------
static constexpr size_t OFF_F0T  = 0;         // [4][4096][8] f32
static constexpr size_t OFF_F1T  = 524288;    // [4][4096][32]
static constexpr size_t OFF_F2T  = 3670016;   // [4][2048][64]
static constexpr size_t OFF_F3T  = 5767168;   // [4][2048][64]
static constexpr size_t OFF_CQ1  = 8912896;   // [4][3][2048]
static constexpr size_t OFF_CQ2  = 9011200;   // [4][3][1024]
static constexpr size_t OFF_H    = 9060352;   // [4][Nq][16][Cout] 33.55MB -> ends 42614784
static constexpr size_t OFF_IDX1 = 42614784;  // [4][4096][16] i32
static constexpr size_t OFF_IDX2 = 43663360;  // [4][2048][16]
static constexpr size_t OFF_IDX3 = 44187648;  // [4][2048][16]
static constexpr size_t OFF_IDX4 = 44711936;  // [4][1024][16]
static constexpr size_t OFF_FPS1 = 44974080;  // [4][2048] i32
static constexpr size_t OFF_FPS2 = 45006848;  // [4][1024] i32
static constexpr size_t OFF_WD1  = 45023232;  // [32][8]
static constexpr size_t OFF_WD2  = 45024256;  // [64][32]
static constexpr size_t OFF_WD3  = 45032448;  // [64][64]
static constexpr size_t OFF_WD4  = 45048832;  // [128][64]
static constexpr size_t OFF_STAT = 45081600;  // 128 doubles
// part1 [4][4096][4][16]u64 = 8.39MB; parts 2/3/4 reuse its footprint after merge1.
static constexpr size_t OFF_PART  = 45099008;             // part1 ends 53487616
static constexpr size_t OFF_PART2 = OFF_PART;             // 4.19MB
static constexpr size_t OFF_PART3 = OFF_PART + 4194304;   // 2.10MB
static constexpr size_t OFF_PART4 = OFF_PART + 6291456;   // 2.10MB
static constexpr size_t OFF_CAND0 = 53487616;             // [4][4096] float4 = 256KB
static constexpr size_t OFF_CAND1 = 53749760;             // [4][2048] float4 = 128KB -> ends 53880832

// d_out offsets (floats): coor | f | xyz1 | point1 | inpc_f
static constexpr size_t OUT_COOR = 0;        // [4][3][1024]
static constexpr size_t OUT_F    = 12288;    // [4][128][1024]
static constexpr size_t OUT_XYZ1 = 536576;   // [4][3][2048]
static constexpr size_t OUT_PT1  = 561152;   // [4][64][2048]
static constexpr size_t OUT_INPC = 1085440;  // [4][8][4096]

// ---------------- DPP wave-max on u64 keys ----------------
template<int CTRL>
__device__ __forceinline__ unsigned long long dpp_max64(unsigned long long k) {
  unsigned lo = (unsigned)k, hi = (unsigned)(k >> 32);
  unsigned olo = (unsigned)__builtin_amdgcn_update_dpp((int)lo, (int)lo, CTRL, 0xF, 0xF, false);
  unsigned ohi = (unsigned)__builtin_amdgcn_update_dpp((int)hi, (int)hi, CTRL, 0xF, 0xF, false);
  unsigned long long o = ((unsigned long long)ohi << 32) | olo;
  return o > k ? o : k;
}

// ---------------- prep: zero stats + weight deltas ----------------
__device__ __forceinline__ void prep_dev(
    int vb, const float* __restrict__ w1, const float* __restrict__ w2,
    const float* __restrict__ w3, const float* __restrict__ w4,
    float* __restrict__ wd1, float* __restrict__ wd2,
    float* __restrict__ wd3, float* __restrict__ wd4,
    double* __restrict__ stats)
{
  int t = vb * 256 + threadIdx.x;
  if (t < 128) stats[t] = 0.0;
  if (t < 32 * 8)   { int o = t / 8,  c = t % 8;  wd1[t] = w1[o*16  + 8   + c] - w1[o*16  + c]; }
  if (t < 64 * 32)  { int o = t / 32, c = t % 32; wd2[t] = w2[o*64  + 32  + c] - w2[o*64  + c]; }
  if (t < 64 * 64)  { int o = t / 64, c = t % 64; wd3[t] = w3[o*128 + 64  + c] - w3[o*128 + c]; }
  if (t < 128 * 64) { int o = t / 64, c = t % 64; wd4[t] = w4[o*128 + 64  + c] - w4[o*128 + c]; }
}

// ---------------- input linear ----------------
__device__ __forceinline__ void linear_dev(
    int vb, const float* __restrict__ x, const float* __restrict__ w_in,
    const float* __restrict__ b_in, float* __restrict__ f0t,
    float* __restrict__ out_inpc)
{
  int t = vb * 256 + threadIdx.x;
  int n = t & (NPT0 - 1);
  int b = t >> 12;
  float x0 = x[(size_t)b*3*NPT0 + n];
  float x1 = x[(size_t)b*3*NPT0 + NPT0 + n];
  float x2 = x[(size_t)b*3*NPT0 + 2*NPT0 + n];
#pragma unroll
  for (int o = 0; o < 8; ++o) {
    float v = __fmul_rn(w_in[o*3], x0);
    v = fmaf(w_in[o*3+1], x1, v);
    v = fmaf(w_in[o*3+2], x2, v);
    v = __fadd_rn(v, b_in[o]);
    f0t[(size_t)t * 8 + o] = v;
    out_inpc[((size_t)b*8 + o)*NPT0 + n] = v;
  }
}

// ---- kNN partial (packed candidates, 256 thr): top-16 per (query, CS slice) --
// key = (flipbits(d) << 32) | j : ascending == (d asc, idx asc) == lax.top_k ties.
template<int CS>
__device__ __forceinline__ void knnp_pack_dev(
    int vb, const float* __restrict__ cq, const float4* __restrict__ candPack,
    unsigned long long* __restrict__ part, int Nq, int Nk)
{
  const int slices = Nk / CS;
  int s  = vb % slices;
  int r  = vb / slices;
  int qb = r % (Nq >> 8);
  int b  = r / (Nq >> 8);
  int t  = threadIdx.x;
  int q  = qb*256 + t;
  const float* cqb = cq + (size_t)b*3*Nq;
  float qx = cqb[q], qy = cqb[Nq + q], qz = cqb[2*Nq + q];
  float sqq = __fadd_rn(__fadd_rn(__fmul_rn(qx,qx), __fmul_rn(qy,qy)), __fmul_rn(qz,qz));

  const float4* cp = candPack + (size_t)b*Nk + s*CS;
  int jbase = s*CS;

  unsigned long long bd[16];
#pragma unroll
  for (int sl = 0; sl < 16; ++sl) bd[sl] = ~0ull;
  unsigned long long wk = ~0ull; int ws = 0;

#pragma unroll 4
  for (int jj = 0; jj < CS; ++jj) {
    float4 c = cp[jj];                       // wave-uniform -> scalar load
    float dot = __fmul_rn(c.x, qx);
    dot = fmaf(c.y, qy, dot);
    dot = fmaf(c.z, qz, dot);
    float d = __fsub_rn(__fadd_rn(sqq, c.w), __fmul_rn(2.0f, dot));
    unsigned u = __float_as_uint(d);
    u ^= (0x80000000u | (unsigned)((int)u >> 31));
    unsigned long long key = ((unsigned long long)u << 32) | (unsigned)(jbase + jj);
    if (key < wk) {
      unsigned long long nw = 0; int nws = 0;
#pragma unroll
      for (int sl = 0; sl < 16; ++sl) {
        bool rep = (sl == ws);
        unsigned long long v = rep ? key : bd[sl];
        bd[sl] = v;
        bool g = v > nw;
        nw = g ? v : nw; nws = g ? sl : nws;
      }
      wk = nw; ws = nws;
    }
  }
  unsigned long long* op = part + (((size_t)b*Nq + q)*(size_t)slices + s)*16;
#pragma unroll
  for (int sl = 0; sl < 16; ++sl) op[sl] = bd[sl];
}

// ---- kNN partial (LDS-staged, 256 thr) — only where no FPS co-runs (knn4) --
__device__ __forceinline__ void knnp_lds_dev(
    int vb, const float* __restrict__ cq, const float* __restrict__ ck,
    unsigned long long* __restrict__ part, int Nq, int Nk, int slices, void* smem)
{
  const int CS = 512;
  int s  = vb % slices;
  int r  = vb / slices;
  int qb = r % (Nq >> 8);
  int b  = r / (Nq >> 8);
  float4* cand = (float4*)smem;
  int t = threadIdx.x;
  const float* ckb = ck + (size_t)b*3*Nk;
  for (int jj = t; jj < CS; jj += 256) {
    int j = s*CS + jj;
    float xx = ckb[j], yy = ckb[Nk + j], zz = ckb[2*Nk + j];
    float sq = __fadd_rn(__fadd_rn(__fmul_rn(xx,xx), __fmul_rn(yy,yy)), __fmul_rn(zz,zz));
    cand[jj] = make_float4(xx, yy, zz, sq);
  }
  __syncthreads();
  int q = qb*256 + t;
  const float* cqb = cq + (size_t)b*3*Nq;
  float qx = cqb[q], qy = cqb[Nq + q], qz = cqb[2*Nq + q];
  float sqq = __fadd_rn(__fadd_rn(__fmul_rn(qx,qx), __fmul_rn(qy,qy)), __fmul_rn(qz,qz));

  unsigned long long bd[16];
#pragma unroll
  for (int sl = 0; sl < 16; ++sl) bd[sl] = ~0ull;
  unsigned long long wk = ~0ull; int ws = 0;

  for (int jj = 0; jj < CS; ++jj) {
    float4 c = cand[jj];
    float dot = __fmul_rn(c.x, qx);
    dot = fmaf(c.y, qy, dot);
    dot = fmaf(c.z, qz, dot);
    float d = __fsub_rn(__fadd_rn(sqq, c.w), __fmul_rn(2.0f, dot));
    unsigned u = __float_as_uint(d);
    u ^= (0x80000000u | (unsigned)((int)u >> 31));
    unsigned long long key = ((unsigned long long)u << 32) | (unsigned)(s*CS + jj);
    if (key < wk) {
      unsigned long long nw = 0; int nws = 0;
#pragma unroll
      for (int sl = 0; sl < 16; ++sl) {
        bool rep = (sl == ws);
        unsigned long long v = rep ? key : bd[sl];
        bd[sl] = v;
        bool g = v > nw;
        nw = g ? v : nw; nws = g ? sl : nws;
      }
      wk = nw; ws = nws;
    }
  }
  unsigned long long* op = part + (((size_t)b*Nq + q)*(size_t)slices + s)*16;
#pragma unroll
  for (int sl = 0; sl < 16; ++sl) op[sl] = bd[sl];
}

// ---------------- kNN merge: 16 smallest of slices*16 ----------
__device__ __forceinline__ void merge_dev(
    int vb, const unsigned long long* __restrict__ part, int* __restrict__ idx,
    int slices)
{
  int t = vb * 256 + threadIdx.x;
  const unsigned long long* ip = part + (size_t)t * slices * 16;
  unsigned long long bd[16];
#pragma unroll
  for (int sl = 0; sl < 16; ++sl) bd[sl] = ~0ull;
  unsigned long long wk = ~0ull; int ws = 0;
  int n = slices * 16;
  for (int i = 0; i < n; ++i) {
    unsigned long long key = ip[i];
    if (key < wk) {
      unsigned long long nw = 0; int nws = 0;
#pragma unroll
      for (int sl = 0; sl < 16; ++sl) {
        bool rep = (sl == ws);
        unsigned long long v = rep ? key : bd[sl];
        bd[sl] = v;
        bool g = v > nw;
        nw = g ? v : nw; nws = g ? sl : nws;
      }
      wk = nw; ws = nws;
    }
  }
  int* op = idx + (size_t)t * 16;
#pragma unroll
  for (int sl = 0; sl < 16; ++sl) op[sl] = (int)(bd[sl] & 0xFFFFFFFFull);
}

// ------- FPS (256 thr): NO global ops in the serial loop --------------------
// key = (bits(nd) << 32) | ~j ; max key == max nd, ties -> lowest j (argmax).
// Selections recorded to LDS; fidx/coords written out in a parallel epilogue,
// so the compiler's pre-barrier s_waitcnt drains only LDS (cheap), not stores.
template<int NN, int M, int PPT>
__device__ __forceinline__ void fps_dev(
    int b, const float* __restrict__ coor, int* __restrict__ fidx_all,
    float* __restrict__ ca_all, float* __restrict__ co_all, void* smem)
{
  float4* sc = (float4*)smem;                      // [NN] (x,y,z,0)
  int* sidx  = (int*)(sc + NN);                    // [M]
  unsigned long long* part = (unsigned long long*)(sidx + M);  // [2][4]
  int t = threadIdx.x, lane = t & 63;
  const float* cb = coor + (size_t)b*3*NN;
  float px[PPT], py[PPT], pz[PPT], pd[PPT];
#pragma unroll
  for (int i = 0; i < PPT; ++i) {
    int j = i*256 + t;
    px[i] = cb[j]; py[i] = cb[NN + j]; pz[i] = cb[2*NN + j];
    pd[i] = 1e10f;
    sc[j] = make_float4(px[i], py[i], pz[i], 0.f);
  }
  __syncthreads();
  float4 c0 = sc[0];
  float cx = c0.x, cy = c0.y, cz = c0.z;
  int cur = 0, par = 0;
  for (int it = 0; it < M; ++it) {
    if (t == 0) sidx[it] = cur;
    float bv = -1.0f; int bslot = 0;
#pragma unroll
    for (int i = 0; i < PPT; ++i) {
      float dx = __fsub_rn(px[i], cx);
      float dy = __fsub_rn(py[i], cy);
      float dz = __fsub_rn(pz[i], cz);
      float d = __fadd_rn(__fadd_rn(__fmul_rn(dx,dx), __fmul_rn(dy,dy)), __fmul_rn(dz,dz));
      float nd = fminf(pd[i], d);
      pd[i] = nd;
      bool g = nd > bv;
      bv = g ? nd : bv;
      bslot = g ? i : bslot;
    }
    unsigned bij = ~(unsigned)(bslot * 256 + t);
    unsigned long long k = ((unsigned long long)__float_as_uint(bv) << 32) | bij;
    k = dpp_max64<0x111>(k);   // row_shr:1
    k = dpp_max64<0x112>(k);   // row_shr:2
    k = dpp_max64<0x114>(k);   // row_shr:4
    k = dpp_max64<0x118>(k);   // row_shr:8
    k = dpp_max64<0x142>(k);   // row_bcast:15
    k = dpp_max64<0x143>(k);   // row_bcast:31  -> lane 63 has wave max
    if (lane == 63) part[par*4 + (t >> 6)] = k;
    __syncthreads();
    ulonglong2 p01 = *(const ulonglong2*)&part[par*4 + 0];
    ulonglong2 p23 = *(const ulonglong2*)&part[par*4 + 2];
    unsigned long long k0 = p01.x > p01.y ? p01.x : p01.y;
    unsigned long long k2 = p23.x > p23.y ? p23.x : p23.y;
    k0 = k2 > k0 ? k2 : k0;
    cur = (int)(~(unsigned)(k0 & 0xFFFFFFFFull));
    float4 cc = sc[cur];
    cx = cc.x; cy = cc.y; cz = cc.z;
    par ^= 1;   // double-buffered partials -> single barrier per step
  }
  __syncthreads();
  // parallel epilogue: all global stores happen here, off the serial chain
  int* fidx = fidx_all + b*M;
  float* ca = ca_all + (size_t)b*3*M;
  float* co = co_all + (size_t)b*3*M;
  for (int it = t; it < M; it += 256) {
    int s = sidx[it];
    float4 cc = sc[s];
    fidx[it] = s;
    ca[it] = cc.x; ca[M + it] = cc.y; ca[2*M + it] = cc.z;
    co[it] = cc.x; co[M + it] = cc.y; co[2*M + it] = cc.z;
  }
}

// ------- fused (optional FPS-gather) + graph-conv + fp64 GN stats ----------
template<int C, int COUT, int OC>
__device__ __forceinline__ void passA_dev(
    int vb, const float* __restrict__ xq, const float* __restrict__ xk,
    const int* __restrict__ idx, const float* __restrict__ w,
    const float* __restrict__ wdl, float* __restrict__ h,
    double* __restrict__ stats, int Nq, int Nk,
    const int* __restrict__ qmap, int NqSrc, void* smem)
{
  constexpr int NCH = COUT / OC;
  constexpr int GS  = COUT / 4;
  float* sxq   = (float*)smem;          // [16][C]
  float* sbase = sxq + 16*C;            // [16][COUT+1]
  int qb = Nq >> 4;
  int b = vb / qb, nb = vb % qb;
  int n0 = nb << 4;
  int t = threadIdx.x;
  for (int i = t; i < 16*C; i += 256) {
    int nn = i / C, cc = i % C;
    int qrow = qmap ? qmap[b*Nq + n0 + nn] : (n0 + nn);
    sxq[nn*C + cc] = xq[((size_t)b*NqSrc + qrow)*C + cc];
  }
  __syncthreads();
  for (int i = t; i < 16*COUT; i += 256) {
    int nn = i / COUT, o = i % COUT;
    float acc = 0.f;
#pragma unroll 4
    for (int c = 0; c < C; ++c) acc = fmaf(wdl[o*C + c], sxq[nn*C + c], acc);
    sbase[nn*(COUT+1) + o] = acc;
  }
  __syncthreads();
  int lane = t & 63;
  int n_loc = t >> 4, kk = t & 15;
  int kidx = idx[((size_t)b*Nq + n0 + n_loc)*16 + kk];
  const float* xr = xk + ((size_t)b*Nk + kidx)*C;
  float* hrow = h + (((size_t)b*Nq + n0 + n_loc)*16 + kk)*(size_t)COUT;
#pragma unroll 1
  for (int oc = 0; oc < NCH; ++oc) {
    int o0 = oc * OC;
    float acc[OC];
#pragma unroll
    for (int oi = 0; oi < OC; ++oi) acc[oi] = sbase[n_loc*(COUT+1) + o0 + oi];
#pragma unroll 1
    for (int c4 = 0; c4 < C/4; ++c4) {
      float4 v = *(const float4*)(xr + c4*4);
#pragma unroll
      for (int oi = 0; oi < OC; ++oi) {
        const float* wr = w + (size_t)(o0 + oi)*(2*C) + c4*4;  // wave-uniform
        acc[oi] = fmaf(wr[0], v.x, acc[oi]);
        acc[oi] = fmaf(wr[1], v.y, acc[oi]);
        acc[oi] = fmaf(wr[2], v.z, acc[oi]);
        acc[oi] = fmaf(wr[3], v.w, acc[oi]);
      }
    }
#pragma unroll
    for (int oi = 0; oi < OC; ++oi) hrow[o0 + oi] = acc[oi];
    double s = 0.0, s2 = 0.0;
#pragma unroll
    for (int oi = 0; oi < OC; ++oi) { double dv = (double)acc[oi]; s += dv; s2 += dv*dv; }
#pragma unroll
    for (int mm = 1; mm < 64; mm <<= 1) {
      s  += __shfl_xor(s,  mm, 64);
      s2 += __shfl_xor(s2, mm, 64);
    }
    if (lane == 0) {
      int g = o0 / GS;
      atomicAdd(&stats[((size_t)b*4 + g)*2],     s);
      atomicAdd(&stats[((size_t)b*4 + g)*2 + 1], s2);
    }
  }
}

template<int C, int COUT, int OC>
__global__ __launch_bounds__(256) void k_passA(
    const float* __restrict__ xq, const float* __restrict__ xk,
    const int* __restrict__ idx, const float* __restrict__ w,
    const float* __restrict__ wdl, float* __restrict__ h,
    double* __restrict__ stats, int Nq, int Nk,
    const int* __restrict__ qmap, int NqSrc)
{
  extern __shared__ char smem[];
  passA_dev<C,COUT,OC>(blockIdx.x, xq, xk, idx, w, wdl, h, stats, Nq, Nk,
                       qmap, NqSrc, smem);
}

// -------- pass B with inline GN finalize: normalize + leaky + max over k ----
__device__ __forceinline__ void passB_dev(
    int vb, const float* __restrict__ h, const double* __restrict__ stats,
    const float* __restrict__ gw, const float* __restrict__ gb,
    float* __restrict__ ft, float* __restrict__ ocn, int Nq, int COUT)
{
  int t = vb * 256 + threadIdx.x;
  int o = t % COUT;
  int r = t / COUT;
  int n = r % Nq;
  int b = r / Nq;
  int GS = COUT / 4, g = o / GS;
  double cnt = (double)GS * (double)Nq * 16.0;
  double su = stats[((size_t)b*4 + g)*2];
  double s2 = stats[((size_t)b*4 + g)*2 + 1];
  double mean = su / cnt;
  double var = s2 / cnt - mean * mean;
  float vf = (float)var; if (vf < 0.f) vf = 0.f;
  float inv = 1.0f / sqrtf(vf + 1e-5f);
  float A = gw[o] * inv;
  float Bb = gb[o] - (float)mean * A;
  const float* hp = h + (((size_t)b*Nq + n)*16)*(size_t)COUT + o;
  float m = -FLT_MAX;
#pragma unroll
  for (int k = 0; k < 16; ++k) {
    float v = hp[(size_t)k*COUT];
    float y = fmaf(v, A, Bb);
    y = (y >= 0.f) ? y : 0.2f*y;
    m = fmaxf(m, y);
  }
  if (ft)  ft[((size_t)b*Nq + n)*COUT + o] = m;
  if (ocn) ocn[((size_t)b*COUT + o)*Nq + n] = m;
}

__global__ __launch_bounds__(256) void k_passB(
    const float* __restrict__ h, const double* __restrict__ stats,
    const float* __restrict__ gw, const float* __restrict__ gb,
    float* __restrict__ ft, float* __restrict__ ocn, int Nq, int COUT)
{
  passB_dev(blockIdx.x, h, stats, gw, gb, ft, ocn, Nq, COUT);
}

// ---- PRE: pack0(x) || prep || linear_in ------------------------------------
__global__ __launch_bounds__(256) void k_pre(
    const float* __restrict__ x, const float* __restrict__ w_in,
    const float* __restrict__ b_in, float* __restrict__ f0t,
    float* __restrict__ outInpc,
    const float* __restrict__ w1, const float* __restrict__ w2,
    const float* __restrict__ w3, const float* __restrict__ w4,
    float* __restrict__ wd1, float* __restrict__ wd2,
    float* __restrict__ wd3, float* __restrict__ wd4,
    double* __restrict__ stats, float4* __restrict__ cand0)
{
  int vb = blockIdx.x;
  if (vb < 64) {
    int g = vb*256 + threadIdx.x;       // [0,16384)
    int b = g >> 12, n = g & 4095;
    const float* xb = x + (size_t)b*3*4096;
    float xx = xb[n], yy = xb[4096 + n], zz = xb[2*4096 + n];
    float sq = __fadd_rn(__fadd_rn(__fmul_rn(xx,xx), __fmul_rn(yy,yy)), __fmul_rn(zz,zz));
    cand0[g] = make_float4(xx, yy, zz, sq);
  }
  else if (vb < 96) prep_dev(vb - 64, w1, w2, w3, w4, wd1, wd2, wd3, wd4, stats);
  else              linear_dev(vb - 96, x, w_in, b_in, f0t, outInpc);
}

// ---- MEGA A: FPS1 || knn1 partials (packed) --------------------------------
__global__ __launch_bounds__(256) void k_megaA(
    const float* __restrict__ x, int* __restrict__ fps1,
    float* __restrict__ cq1, float* __restrict__ outXyz1,
    const float4* __restrict__ cand0, unsigned long long* __restrict__ part1)
{
  extern __shared__ char smem[];
  int vb = blockIdx.x;
  if (vb < 4) fps_dev<4096,2048,16>(vb, x, fps1, cq1, outXyz1, smem);
  else        knnp_pack_dev<1024>(vb - 4, x, cand0, part1, 4096, 4096);
}

// ---- MERGE-P: merge1 || pack1(cq1) -----------------------------------------
__global__ __launch_bounds__(256) void k_mergeP(
    const unsigned long long* __restrict__ part1, int* __restrict__ idx1,
    const float* __restrict__ cq1, float4* __restrict__ cand1)
{
  int vb = blockIdx.x;
  if (vb < 64) merge_dev(vb, part1, idx1, 4);
  else {
    int g = (vb - 64)*256 + threadIdx.x;   // [0,8192)
    int b = g >> 11, n = g & 2047;
    const float* cb = cq1 + (size_t)b*3*2048;
    float xx = cb[n], yy = cb[2048 + n], zz = cb[2*2048 + n];
    float sq = __fadd_rn(__fadd_rn(__fmul_rn(xx,xx), __fmul_rn(yy,yy)), __fmul_rn(zz,zz));
    cand1[g] = make_float4(xx, yy, zz, sq);
  }
}

// ---- MEGA B: FPS2 || knn2p || knn3p || passA1 ------------------------------
__global__ __launch_bounds__(256) void k_megaB(
    const float* __restrict__ cq1, const float4* __restrict__ cand0,
    const float4* __restrict__ cand1,
    int* __restrict__ fps2, float* __restrict__ cq2, float* __restrict__ outCoor,
    unsigned long long* __restrict__ part2, unsigned long long* __restrict__ part3,
    const float* __restrict__ f0t, const int* __restrict__ idx1,
    const float* __restrict__ w1, const float* __restrict__ wd1,
    float* __restrict__ h, double* __restrict__ st1)
{
  extern __shared__ char smem[];
  int vb = blockIdx.x;
  if      (vb < 4)          fps_dev<2048,1024,8>(vb, cq1, fps2, cq2, outCoor, smem);
  else if (vb < 4 + 128)    knnp_pack_dev<1024>(vb - 4,   cq1, cand0, part2, 2048, 4096);
  else if (vb < 4 + 128+64) knnp_pack_dev<1024>(vb - 132, cq1, cand1, part3, 2048, 2048);
  else                      passA_dev<8,32,8>(vb - 196, f0t, f0t, idx1, w1, wd1,
                                              h, st1, 4096, 4096, nullptr, 4096, smem);
}

// ---- MEGA C: knn4p (LDS) || merge2 || merge3 || passB1 ---------------------
__global__ __launch_bounds__(256) void k_megaC(
    const float* __restrict__ cq2, const float* __restrict__ cq1,
    unsigned long long* __restrict__ part4,
    const unsigned long long* __restrict__ part2, int* __restrict__ idx2,
    const unsigned long long* __restrict__ part3, int* __restrict__ idx3,
    const float* __restrict__ h, const double* __restrict__ st1,
    const float* __restrict__ g1w, const float* __restrict__ g1b,
    float* __restrict__ f1t)
{
  extern __shared__ char smem[];
  int vb = blockIdx.x;
  if      (vb < 64)  knnp_lds_dev(vb, cq2, cq1, part4, 1024, 2048, 4, smem);
  else if (vb < 96)  merge_dev(vb - 64, part2, idx2, 4);
  else if (vb < 128) merge_dev(vb - 96, part3, idx3, 2);
  else               passB_dev(vb - 128, h, st1, g1w, g1b, f1t, nullptr, 4096, 32);
}

// ---- MEGA D: merge4 || passA2 (FPS1-gathered xq) ---------------------------
__global__ __launch_bounds__(256) void k_megaD(
    const unsigned long long* __restrict__ part4, int* __restrict__ idx4,
    const float* __restrict__ f1t, const int* __restrict__ idx2,
    const float* __restrict__ w2, const float* __restrict__ wd2,
    float* __restrict__ h, double* __restrict__ st2,
    const int* __restrict__ fps1)
{
  extern __shared__ char smem[];
  int vb = blockIdx.x;
  if (vb < 16) merge_dev(vb, part4, idx4, 4);
  else         passA_dev<32,64,16>(vb - 16, f1t, f1t, idx2, w2, wd2, h, st2,
                                   2048, 4096, fps1, 4096, smem);
}

// ---------------- launch ----------------
extern "C" void kernel_launch(void* const* d_in, const int* in_sizes, int n_in,
                              void* d_out, int out_size, void* d_ws, size_t ws_size,
                              hipStream_t stream)
{
  (void)in_sizes; (void)n_in; (void)out_size; (void)ws_size;
  const float* x    = (const float*)d_in[0];
  const float* w_in = (const float*)d_in[1];
  const float* b_in = (const float*)d_in[2];
  const float* w1   = (const float*)d_in[3];
  const float* g1w  = (const float*)d_in[4];
  const float* g1b  = (const float*)d_in[5];
  const float* w2   = (const float*)d_in[6];
  const float* g2w  = (const float*)d_in[7];
  const float* g2b  = (const float*)d_in[8];
  const float* w3   = (const float*)d_in[9];
  const float* g3w  = (const float*)d_in[10];
  const float* g3b  = (const float*)d_in[11];
  const float* w4   = (const float*)d_in[12];
  const float* g4w  = (const float*)d_in[13];
  const float* g4b  = (const float*)d_in[14];
  float* out = (float*)d_out;
  char*  wsb = (char*)d_ws;

  float* f0t  = (float*)(wsb + OFF_F0T);
  float* f1t  = (float*)(wsb + OFF_F1T);
  float* f2t  = (float*)(wsb + OFF_F2T);
  float* f3t  = (float*)(wsb + OFF_F3T);
  float* cq1  = (float*)(wsb + OFF_CQ1);
  float* cq2  = (float*)(wsb + OFF_CQ2);
  float* h    = (float*)(wsb + OFF_H);
  int*   idx1 = (int*)(wsb + OFF_IDX1);
  int*   idx2 = (int*)(wsb + OFF_IDX2);
  int*   idx3 = (int*)(wsb + OFF_IDX3);
  int*   idx4 = (int*)(wsb + OFF_IDX4);
  int*   fps1 = (int*)(wsb + OFF_FPS1);
  int*   fps2 = (int*)(wsb + OFF_FPS2);
  float* wd1  = (float*)(wsb + OFF_WD1);
  float* wd2  = (float*)(wsb + OFF_WD2);
  float* wd3  = (float*)(wsb + OFF_WD3);
  float* wd4  = (float*)(wsb + OFF_WD4);
  double* statAll = (double*)(wsb + OFF_STAT);
  double* st1 = statAll, *st2 = statAll + 32, *st3 = statAll + 64, *st4 = statAll + 96;
  unsigned long long* part1 = (unsigned long long*)(wsb + OFF_PART);
  unsigned long long* part2 = (unsigned long long*)(wsb + OFF_PART2);
  unsigned long long* part3 = (unsigned long long*)(wsb + OFF_PART3);
  unsigned long long* part4 = (unsigned long long*)(wsb + OFF_PART4);
  float4* cand0 = (float4*)(wsb + OFF_CAND0);
  float4* cand1 = (float4*)(wsb + OFF_CAND1);

  float* outCoor = out + OUT_COOR;
  float* outF    = out + OUT_F;
  float* outXyz1 = out + OUT_XYZ1;
  float* outPt1  = out + OUT_PT1;
  float* outInpc = out + OUT_INPC;

  // PRE: pack0 || prep || linear_in
  k_pre<<<160, 256, 0, stream>>>(x, w_in, b_in, f0t, outInpc,
      w1, w2, w3, w4, wd1, wd2, wd3, wd4, statAll, cand0);

  // A: FPS1 || knn1p     (FPS LDS: 4096*16 + 2048*4 + 64 = 73792 B)
  k_megaA<<<260, 256, 73792, stream>>>(x, fps1, cq1, outXyz1, cand0, part1);

  // merge1 || pack1
  k_mergeP<<<96, 256, 0, stream>>>(part1, idx1, cq1, cand1);

  // B: FPS2 || knn2p || knn3p || passA1  (FPS LDS: 2048*16+1024*4+64 = 36928 B)
  k_megaB<<<1220, 256, 36928, stream>>>(
      cq1, cand0, cand1, fps2, cq2, outCoor, part2, part3, f0t, idx1, w1, wd1, h, st1);

  // C: knn4p || merge2 || merge3 || passB1
  k_megaC<<<2176, 256, 8192, stream>>>(
      cq2, cq1, part4, part2, idx2, part3, idx3, h, st1, g1w, g1b, f1t);

  // D: merge4 || passA2
  k_megaD<<<528, 256, 6208, stream>>>(part4, idx4, f1t, idx2, w2, wd2, h, st2, fps1);

  // stage 2/3/4 tail
  k_passB<<<2048, 256, 0, stream>>>(h, st2, g2w, g2b, f2t, outPt1, 2048, 64);
  k_passA<64,64,16><<<512, 256, 8256, stream>>>(f2t, f2t, idx3, w3, wd3, h, st3,
                                                2048, 2048, nullptr, 2048);
  k_passB<<<2048, 256, 0, stream>>>(h, st3, g3w, g3b, f3t, nullptr, 2048, 64);
  k_passA<64,128,16><<<256, 256, 12352, stream>>>(f3t, f3t, idx4, w4, wd4, h, st4,
                                                  1024, 2048, fps2, 2048);
  k_passB<<<2048, 256, 0, stream>>>(h, st4, g4w, g4b, nullptr, outF, 1024, 128);
}